// Round 2
// baseline (87.954 us; speedup 1.0000x reference)
//
#include <hip/hip_runtime.h>

// CenterLoss: out = mean_i ||x_i - centers[labels_i]||^2
// B=16384, D=512, C=4000.
//
// Stage 1: one 64-lane wave per 4 consecutive rows. 16 float4 x-loads issued
//          non-temporally (x is read-once; keep centers L2-resident) plus
//          16 float4 center-loads. ~90 VGPR -> 4 waves/SIMD
//          (__launch_bounds__(256,4)); 4096 waves cover 16384 rows.
// Stage 2: one block, 256 threads, one float4 per thread over 1024 partials.
//
// NOTE: __builtin_nontemporal_load requires a NATIVE vector type, not
// HIP_vector_type<float,4> — use clang ext_vector_type(4) float.

#define B_SIZE 16384
#define D_SIZE 512
#define S1_BLOCKS 1024   // 1024 blocks * 4 waves * 4 rows = 16384 rows

typedef float vf4 __attribute__((ext_vector_type(4)));

__global__ __launch_bounds__(256, 4) void center_loss_stage1(
    const float* __restrict__ x,
    const int* __restrict__ labels,
    const float* __restrict__ centers,
    float* __restrict__ partials) {

    const int lane = threadIdx.x & 63;
    const int wave = threadIdx.x >> 6;                 // 4 waves per block
    const int gw   = (blockIdx.x << 2) + wave;         // global wave id [0,4096)
    const int rbase = gw << 2;                         // 4 consecutive rows

    // labels for 4 rows in one 16B load (wave-uniform address -> broadcast)
    const int4 lab = *reinterpret_cast<const int4*>(labels + rbase);

    // x: row r is 128 float4; lane covers 2 consecutive float4 (32B/lane)
    const vf4* xp = reinterpret_cast<const vf4*>(x)
                  + (size_t)rbase * 128 + (lane << 1);

    // issue all 8 x loads first (independent of the label load), non-temporal
    vf4 x0a = __builtin_nontemporal_load(xp + 0);
    vf4 x0b = __builtin_nontemporal_load(xp + 1);
    vf4 x1a = __builtin_nontemporal_load(xp + 128);
    vf4 x1b = __builtin_nontemporal_load(xp + 129);
    vf4 x2a = __builtin_nontemporal_load(xp + 256);
    vf4 x2b = __builtin_nontemporal_load(xp + 257);
    vf4 x3a = __builtin_nontemporal_load(xp + 384);
    vf4 x3b = __builtin_nontemporal_load(xp + 385);

    const vf4* cb = reinterpret_cast<const vf4*>(centers);
    const vf4* c0 = cb + (size_t)lab.x * 128 + (lane << 1);
    const vf4* c1 = cb + (size_t)lab.y * 128 + (lane << 1);
    const vf4* c2 = cb + (size_t)lab.z * 128 + (lane << 1);
    const vf4* c3 = cb + (size_t)lab.w * 128 + (lane << 1);

    vf4 c0a = c0[0], c0b = c0[1];
    vf4 c1a = c1[0], c1b = c1[1];
    vf4 c2a = c2[0], c2b = c2[1];
    vf4 c3a = c3[0], c3b = c3[1];

    vf4 d0 = x0a - c0a, d1 = x0b - c0b;
    vf4 s = d0 * d0 + d1 * d1;
    d0 = x1a - c1a; d1 = x1b - c1b;
    s += d0 * d0 + d1 * d1;
    d0 = x2a - c2a; d1 = x2b - c2b;
    s += d0 * d0 + d1 * d1;
    d0 = x3a - c3a; d1 = x3b - c3b;
    s += d0 * d0 + d1 * d1;

    float acc = (s.x + s.y) + (s.z + s.w);

    // wave-level reduction over 64 lanes
    #pragma unroll
    for (int off = 32; off > 0; off >>= 1)
        acc += __shfl_down(acc, off, 64);

    __shared__ float partial[4];
    if (lane == 0) partial[wave] = acc;
    __syncthreads();

    if (threadIdx.x == 0)
        partials[blockIdx.x] = (partial[0] + partial[1])
                             + (partial[2] + partial[3]);
}

__global__ __launch_bounds__(256) void center_loss_stage2(
    const float* __restrict__ partials,
    float* __restrict__ out) {

    const int t = threadIdx.x;
    const float4 v = reinterpret_cast<const float4*>(partials)[t];  // 256*4 = 1024
    float acc = (v.x + v.y) + (v.z + v.w);

    const int lane = t & 63;
    const int wave = t >> 6;   // 4 waves

    #pragma unroll
    for (int off = 32; off > 0; off >>= 1)
        acc += __shfl_down(acc, off, 64);

    __shared__ float partial[4];
    if (lane == 0) partial[wave] = acc;
    __syncthreads();

    if (t == 0)
        out[0] = ((partial[0] + partial[1]) + (partial[2] + partial[3]))
               * (1.0f / (float)B_SIZE);
}

extern "C" void kernel_launch(void* const* d_in, const int* in_sizes, int n_in,
                              void* d_out, int out_size, void* d_ws, size_t ws_size,
                              hipStream_t stream) {
    const float* x       = (const float*)d_in[0];
    const int*   labels  = (const int*)d_in[1];
    const float* centers = (const float*)d_in[2];
    float* out      = (float*)d_out;
    float* partials = (float*)d_ws;   // 1024 floats = 4 KB scratch

    center_loss_stage1<<<S1_BLOCKS, 256, 0, stream>>>(x, labels, centers, partials);
    center_loss_stage2<<<1, 256, 0, stream>>>(partials, out);
}

// Round 3
// 83.261 us; speedup vs baseline: 1.0564x; 1.0564x over previous
//
#include <hip/hip_runtime.h>

// CenterLoss: out = mean_i ||x_i - centers[labels_i]||^2
// B=16384, D=512, C=4000.
//
// Round-3: revert to the 2-rows/wave, 2048-block structure (best measured:
// 84.5us). Round-2's 4-rows/wave halved blocks -> 16 waves/CU (vs 32) and
// regressed +3.5us: the gather is TLP/latency-bound, wave count dominates.
// Deltas vs baseline:
//   - __launch_bounds__(256, 8): force VGPR<=64 so 8 waves/SIMD (32/CU) is
//     guaranteed, not left to the register allocator (65 VGPR would silently
//     drop to 6/SIMD).
//   - labels loaded as one int2 (single s_load) instead of two int loads.
//   - stage2: 512 threads x float4 over the 2048 partials.

#define B_SIZE 16384
#define D_SIZE 512
#define S1_BLOCKS 2048   // 2048 blocks * 4 waves * 2 rows = 16384 rows

__global__ __launch_bounds__(256, 8) void center_loss_stage1(
    const float* __restrict__ x,
    const int* __restrict__ labels,
    const float* __restrict__ centers,
    float* __restrict__ partials) {

    const int lane = threadIdx.x & 63;
    const int wave = threadIdx.x >> 6;                 // 4 waves per block
    const int gw   = (blockIdx.x << 2) + wave;         // global wave id [0,8192)
    const int row0 = gw << 1;                          // 2 consecutive rows

    // both labels in one 8B wave-uniform load
    const int2 lab = *reinterpret_cast<const int2*>(labels + row0);

    // x: row r is 128 float4; lane covers 2 consecutive float4 (32B/lane)
    const float4* x0 = reinterpret_cast<const float4*>(x)
                     + (size_t)row0 * 128 + (lane << 1);
    const float4* x1 = x0 + 128;

    const float4* cb = reinterpret_cast<const float4*>(centers);
    const float4* c0 = cb + (size_t)lab.x * 128 + (lane << 1);
    const float4* c1 = cb + (size_t)lab.y * 128 + (lane << 1);

    // issue all 8 loads before any use
    float4 xa0 = x0[0], xb0 = x0[1];
    float4 xa1 = x1[0], xb1 = x1[1];
    float4 ca0 = c0[0], cb0 = c0[1];
    float4 ca1 = c1[0], cb1 = c1[1];

    float acc = 0.0f, d;
    d = xa0.x - ca0.x; acc += d * d;
    d = xa0.y - ca0.y; acc += d * d;
    d = xa0.z - ca0.z; acc += d * d;
    d = xa0.w - ca0.w; acc += d * d;
    d = xb0.x - cb0.x; acc += d * d;
    d = xb0.y - cb0.y; acc += d * d;
    d = xb0.z - cb0.z; acc += d * d;
    d = xb0.w - cb0.w; acc += d * d;
    d = xa1.x - ca1.x; acc += d * d;
    d = xa1.y - ca1.y; acc += d * d;
    d = xa1.z - ca1.z; acc += d * d;
    d = xa1.w - ca1.w; acc += d * d;
    d = xb1.x - cb1.x; acc += d * d;
    d = xb1.y - cb1.y; acc += d * d;
    d = xb1.z - cb1.z; acc += d * d;
    d = xb1.w - cb1.w; acc += d * d;

    // wave-level reduction over 64 lanes
    #pragma unroll
    for (int off = 32; off > 0; off >>= 1)
        acc += __shfl_down(acc, off, 64);

    __shared__ float partial[4];
    if (lane == 0) partial[wave] = acc;
    __syncthreads();

    if (threadIdx.x == 0)
        partials[blockIdx.x] = (partial[0] + partial[1])
                             + (partial[2] + partial[3]);
}

__global__ __launch_bounds__(512) void center_loss_stage2(
    const float* __restrict__ partials,
    float* __restrict__ out) {

    const int t = threadIdx.x;
    const float4 v = reinterpret_cast<const float4*>(partials)[t];  // 512*4 = 2048
    float acc = (v.x + v.y) + (v.z + v.w);

    const int lane = t & 63;
    const int wave = t >> 6;   // 8 waves

    #pragma unroll
    for (int off = 32; off > 0; off >>= 1)
        acc += __shfl_down(acc, off, 64);

    __shared__ float partial[8];
    if (lane == 0) partial[wave] = acc;
    __syncthreads();

    if (t == 0) {
        float s = 0.0f;
        #pragma unroll
        for (int i = 0; i < 8; ++i) s += partial[i];
        out[0] = s * (1.0f / (float)B_SIZE);
    }
}

extern "C" void kernel_launch(void* const* d_in, const int* in_sizes, int n_in,
                              void* d_out, int out_size, void* d_ws, size_t ws_size,
                              hipStream_t stream) {
    const float* x       = (const float*)d_in[0];
    const int*   labels  = (const int*)d_in[1];
    const float* centers = (const float*)d_in[2];
    float* out      = (float*)d_out;
    float* partials = (float*)d_ws;   // 2048 floats = 8 KB scratch

    center_loss_stage1<<<S1_BLOCKS, 256, 0, stream>>>(x, labels, centers, partials);
    center_loss_stage2<<<1, 512, 0, stream>>>(partials, out);
}